// Round 2
// baseline (1077.042 us; speedup 1.0000x reference)
//
#include <hip/hip_runtime.h>
#include <cstdint>
#include <math.h>

#define N_TOK 32768
#define K_CODE 8192
#define DIM 512

#define DECAY_F 0.99f
#define OMD_F   0.01f

// output layout (flat float32, concatenated in return order)
#define OFF_LOSS 16777216            // N*D
#define OFF_PERP 16777217
#define OFF_EMB  16777218            // new_embedding [K*D]
#define OFF_CS   20971522            // new_cs [K]
#define OFF_EMAW 20979714            // new_ema_w [K*D]

// workspace layout (bytes)
// [0, 32768)        counts_int [K] i32   (memset 0)
// [32768, 65536)    cursors [K] i32      (memset 0)
// [65536, 65544)    loss_sum double      (memset 0)
// [65600, 98368)    enorm2 [K] f32
// [98368, 229440)   idx [N] i32
// [229440, 360512)  tokenlist [N] i32
// [360512, 393284)  rowstart [K+1] i32
// bestu u64[N*4] lives in d_out's new_ema_w slot (dead until dw_fin_k)

typedef _Float16 f16;
typedef __attribute__((ext_vector_type(8))) _Float16 f16x8;
typedef __attribute__((ext_vector_type(4))) _Float16 f16x4;
typedef __attribute__((ext_vector_type(4))) float    f32x4;

// split fp32 -> (hi fp16, lo fp16); lo = RN16(x - (float)hi); x - hi exact in fp32
__global__ void split_k(const float* __restrict__ src, f16* __restrict__ hp,
                        f16* __restrict__ lp) {
    size_t gid = (size_t)blockIdx.x * 256 + threadIdx.x;
    float4 v = ((const float4*)src)[gid];
    f16 h0 = (f16)v.x, h1 = (f16)v.y, h2 = (f16)v.z, h3 = (f16)v.w;
    f16 l0 = (f16)(v.x - (float)h0), l1 = (f16)(v.y - (float)h1);
    f16 l2 = (f16)(v.z - (float)h2), l3 = (f16)(v.w - (float)h3);
    *(f16x4*)(hp + gid * 4) = (f16x4){h0, h1, h2, h3};
    *(f16x4*)(lp + gid * 4) = (f16x4){l0, l1, l2, l3};
}

__global__ void enorm_k(const float* __restrict__ emb, float* __restrict__ enorm2) {
    int k = blockIdx.x;
    int lane = threadIdx.x;  // 64
    const float4* row = (const float4*)(emb + (size_t)k * DIM);
    float4 a = row[lane];
    float4 b = row[lane + 64];
    float s = a.x*a.x + a.y*a.y + a.z*a.z + a.w*a.w
            + b.x*b.x + b.y*b.y + b.z*b.z + b.w*b.w;
    #pragma unroll
    for (int off = 32; off > 0; off >>= 1) s += __shfl_down(s, off);
    if (lane == 0) enorm2[k] = s;
}

// MFMA fused GEMM+argmin. Block: 128 tokens x 256-code tiles, sweeping K/4 codes.
// Wave tile: 64 rows x 128 cols (rt=4, ct=8). B frags loaded on-demand (VGPR cap).
// LDS tiles XOR-swizzled: physical colblock = logical ^ ((row>>1)&3)  (colblock = 16 B)
__global__ __launch_bounds__(256, 2) void argmin_mfma(
        const f16* __restrict__ xh, const f16* __restrict__ xl,
        const f16* __restrict__ eh, const f16* __restrict__ el,
        const float* __restrict__ enorm2,
        unsigned long long* __restrict__ bestu) {
    __shared__ f16 sA[2 * 128 * 32];   // [plane][row][k] 16 KB
    __shared__ f16 sB[2 * 256 * 32];   // [plane][row][k] 32 KB

    const int tid  = threadIdx.x;
    const int lane = tid & 63;
    const int wave = tid >> 6;
    const int wr   = wave >> 1;
    const int wc   = wave & 1;
    const int m    = lane & 15;
    const int g4   = lane >> 4;
    const int cbp  = g4 ^ ((m >> 1) & 3);      // swizzled colblock for frag reads

    const int rowBase = blockIdx.x * 128;
    const int kBase   = blockIdx.y * (K_CODE / 4);

    // staging: wave 0->A hi, 1->A lo, 2->B hi, 3->B lo; lane l writes LDS at l*16B
    // A waves stage 8 chunks (128 rows), B waves 16 chunks (256 rows).
    const int srow  = lane >> 2;
    const int scolh = (((lane & 3) ^ ((lane >> 3) & 3)) << 3);  // swizzled source col (halfs)
    char* lbase = (wave < 2) ? ((char*)sA + (wave & 1) * 8192)
                             : ((char*)sB + (wave & 1) * 16384);

    float best[16];
    int   bidx[16];
    #pragma unroll
    for (int i = 0; i < 16; ++i) { best[i] = 3.4e38f; bidx[i] = 0; }

    for (int kt = 0; kt < K_CODE / 4; kt += 256) {
        f32x4 acc[4][8];
        #pragma unroll
        for (int a = 0; a < 4; ++a)
            #pragma unroll
            for (int b = 0; b < 8; ++b)
                acc[a][b] = (f32x4){0.f, 0.f, 0.f, 0.f};

        const f16* gA = (wave == 0 ? xh : xl) + (size_t)rowBase * DIM;
        const f16* gB = (wave == 2 ? eh : el) + (size_t)(kBase + kt) * DIM;
        const f16* gsrc = (wave < 2) ? gA : gB;

        for (int d0 = 0; d0 < DIM; d0 += 32) {
            __syncthreads();
            const f16* g = gsrc + d0 + (size_t)srow * DIM + scolh;
            if (wave < 2) {
                #pragma unroll
                for (int i = 0; i < 8; ++i) {
                    __builtin_amdgcn_global_load_lds(
                        (const __attribute__((address_space(1))) unsigned int*)(g + (size_t)i * 16 * DIM),
                        (__attribute__((address_space(3))) unsigned int*)(lbase + i * 1024),
                        16, 0, 0);
                }
            } else {
                #pragma unroll
                for (int i = 0; i < 16; ++i) {
                    __builtin_amdgcn_global_load_lds(
                        (const __attribute__((address_space(1))) unsigned int*)(g + (size_t)i * 16 * DIM),
                        (__attribute__((address_space(3))) unsigned int*)(lbase + i * 1024),
                        16, 0, 0);
                }
            }
            __syncthreads();

            f16x8 ah[4], al[4];
            #pragma unroll
            for (int rt = 0; rt < 4; ++rt) {
                int off = (wr * 64 + rt * 16 + m) * 32 + cbp * 8;
                ah[rt] = *(const f16x8*)(sA + off);
                al[rt] = *(const f16x8*)(sA + 4096 + off);
            }
            #pragma unroll
            for (int ct = 0; ct < 8; ++ct) {
                int off = (wc * 128 + ct * 16 + m) * 32 + cbp * 8;
                f16x8 bh = *(const f16x8*)(sB + off);
                f16x8 bl = *(const f16x8*)(sB + 8192 + off);
                #pragma unroll
                for (int rt = 0; rt < 4; ++rt) {
                    acc[rt][ct] = __builtin_amdgcn_mfma_f32_16x16x32_f16(ah[rt], bl, acc[rt][ct], 0, 0, 0);
                    acc[rt][ct] = __builtin_amdgcn_mfma_f32_16x16x32_f16(al[rt], bh, acc[rt][ct], 0, 0, 0);
                    acc[rt][ct] = __builtin_amdgcn_mfma_f32_16x16x32_f16(ah[rt], bh, acc[rt][ct], 0, 0, 0);
                }
            }
        }

        // dist = |e|^2 - 2 x.e ; running argmin (ascending col order, strict <)
        int colBase = kBase + kt + wc * 128;
        float e2[8];
        #pragma unroll
        for (int ct = 0; ct < 8; ++ct) e2[ct] = enorm2[colBase + ct * 16 + m];
        #pragma unroll
        for (int rt = 0; rt < 4; ++rt)
            #pragma unroll
            for (int reg = 0; reg < 4; ++reg) {
                float d = 3.4e38f; int c = 0;
                #pragma unroll
                for (int ct = 0; ct < 8; ++ct) {
                    float dist = e2[ct] - 2.0f * acc[rt][ct][reg];
                    if (dist < d) { d = dist; c = colBase + ct * 16 + m; }
                }
                int bi = rt * 4 + reg;
                if (d < best[bi]) { best[bi] = d; bidx[bi] = c; }
            }
    }

    __syncthreads();   // all waves done with sA/sB; reuse as combine scratch
    float* cd = (float*)sA;                 // [128]
    int*   ci = (int*)((char*)sA + 512);    // [128]

    #pragma unroll
    for (int rt = 0; rt < 4; ++rt)
        #pragma unroll
        for (int reg = 0; reg < 4; ++reg) {
            float d = best[rt * 4 + reg];
            int  ix = bidx[rt * 4 + reg];
            #pragma unroll
            for (int off = 1; off < 16; off <<= 1) {
                float od = __shfl_xor(d, off);
                int   oi = __shfl_xor(ix, off);
                if (od < d || (od == d && oi < ix)) { d = od; ix = oi; }
            }
            best[rt * 4 + reg] = d;
            bidx[rt * 4 + reg] = ix;
            if (wc == 1 && m == 0) {
                int tl = rt * 16 + g4 * 4 + reg;
                cd[wr * 64 + tl] = d;
                ci[wr * 64 + tl] = ix;
            }
        }
    __syncthreads();
    if (wc == 0 && m == 0) {
        #pragma unroll
        for (int rt = 0; rt < 4; ++rt)
            #pragma unroll
            for (int reg = 0; reg < 4; ++reg) {
                int tl = rt * 16 + g4 * 4 + reg;
                float d = best[rt * 4 + reg];
                int  ix = bidx[rt * 4 + reg];
                float od = cd[wr * 64 + tl];
                int   oi = ci[wr * 64 + tl];
                if (od < d || (od == d && oi < ix)) { d = od; ix = oi; }
                unsigned int fs = __float_as_uint(d);
                unsigned int key = fs ^ ((fs & 0x80000000u) ? 0xFFFFFFFFu : 0x80000000u);
                unsigned long long u = ((unsigned long long)key << 32) | (unsigned int)ix;
                bestu[(size_t)(rowBase + wr * 64 + tl) * 4 + blockIdx.y] = u;
            }
    }
}

// per token: min over 4 slots -> idx, count histogram
__global__ void bucket1_k(const unsigned long long* __restrict__ bestu,
                          int* __restrict__ idx, int* __restrict__ counts) {
    int n = blockIdx.x * 256 + threadIdx.x;
    const unsigned long long* p = bestu + (size_t)n * 4;
    unsigned long long u = p[0];
    if (p[1] < u) u = p[1];
    if (p[2] < u) u = p[2];
    if (p[3] < u) u = p[3];
    int code = (int)(u & 0xFFFFFFFFull);
    idx[n] = code;
    atomicAdd(&counts[code], 1);
}

// exclusive prefix sum over counts (single block)
__global__ void prefix_k(const int* __restrict__ counts, int* __restrict__ rowstart) {
    __shared__ int part[256];
    __shared__ int partsc[257];
    int t = threadIdx.x;
    int base = t * 32;
    int c[32];
    int s = 0;
    #pragma unroll
    for (int j = 0; j < 32; ++j) { c[j] = counts[base + j]; s += c[j]; }
    part[t] = s;
    __syncthreads();
    if (t == 0) {
        int r = 0;
        for (int i = 0; i < 256; ++i) { partsc[i] = r; r += part[i]; }
        partsc[256] = r;
    }
    __syncthreads();
    int off = partsc[t];
    #pragma unroll
    for (int j = 0; j < 32; ++j) { rowstart[base + j] = off; off += c[j]; }
    if (t == 255) rowstart[K_CODE] = partsc[256];
}

// scatter tokens into CSR lists
__global__ void scatter_k(const int* __restrict__ idx, const int* __restrict__ rowstart,
                          int* __restrict__ cursors, int* __restrict__ tokenlist) {
    int n = blockIdx.x * 256 + threadIdx.x;
    int code = idx[n];
    int pos = atomicAdd(&cursors[code], 1);
    tokenlist[rowstart[code] + pos] = n;
}

// gather q = emb[idx] and exact commitment-loss sum
__global__ void gather_q(const float* __restrict__ x, const float* __restrict__ emb,
                         const int* __restrict__ idx, float* __restrict__ q,
                         double* __restrict__ loss_sum) {
    float ls = 0.f;
    #pragma unroll
    for (int it = 0; it < 8; ++it) {
        size_t g = (size_t)blockIdx.x * 256 + threadIdx.x + (size_t)it * 524288;
        int n = (int)(g >> 7);
        int c = (int)(g & 127);
        float4 ev = ((const float4*)emb)[(size_t)idx[n] * 128 + c];
        float4 xv = ((const float4*)x)[g];
        ((float4*)q)[g] = ev;
        float dx = ev.x - xv.x, dy = ev.y - xv.y, dz = ev.z - xv.z, dw = ev.w - xv.w;
        ls += dx*dx + dy*dy + dz*dz + dw*dw;
    }
    #pragma unroll
    for (int off = 32; off > 0; off >>= 1) ls += __shfl_down(ls, off);
    __shared__ float wsum[4];
    int t = threadIdx.x;
    if ((t & 63) == 0) wsum[t >> 6] = ls;
    __syncthreads();
    if (t == 0) atomicAdd(loss_sum, (double)(wsum[0] + wsum[1] + wsum[2] + wsum[3]));
}

// single block: new_cs normalization, perplexity, loss scalar
__global__ void stats_k(const int* __restrict__ counts, const float* __restrict__ ema_cs,
                        const double* __restrict__ loss_sum, float* __restrict__ out) {
    __shared__ float sraw[K_CODE];
    __shared__ double rn[4], rp[4];
    __shared__ float s_scale;
    int t = threadIdx.x;  // 256
    double ntot = 0.0, pent = 0.0;
    for (int k = t; k < K_CODE; k += 256) {
        float c = (float)counts[k];
        float raw = DECAY_F * ema_cs[k] + OMD_F * c;
        sraw[k] = raw;
        ntot += (double)raw;
        float p = c * (1.0f / N_TOK);
        pent += (double)(p * logf(p + 1e-10f));
    }
    #pragma unroll
    for (int off = 32; off > 0; off >>= 1) {
        ntot += __shfl_down(ntot, off);
        pent += __shfl_down(pent, off);
    }
    if ((t & 63) == 0) { rn[t >> 6] = ntot; rp[t >> 6] = pent; }
    __syncthreads();
    if (t == 0) {
        double nt = rn[0] + rn[1] + rn[2] + rn[3];
        double pe = rp[0] + rp[1] + rp[2] + rp[3];
        s_scale = (float)(nt / (nt + (double)K_CODE * 1e-5));
        out[OFF_LOSS] = (float)(0.25 * (*loss_sum) / ((double)N_TOK * (double)DIM));
        out[OFF_PERP] = (float)exp(-pe);
    }
    __syncthreads();
    float scale = s_scale;
    for (int k = t; k < K_CODE; k += 256)
        out[OFF_CS + k] = (sraw[k] + 1e-5f) * scale;
}

// per code: dw = sum of assigned x rows; fused EMA + divide epilogue
__global__ __launch_bounds__(128) void dw_fin_k(
        const float* __restrict__ x, const float* __restrict__ ema_w,
        const int* __restrict__ rowstart, const int* __restrict__ tokenlist,
        const float* __restrict__ new_cs,
        float* __restrict__ emaw_out, float* __restrict__ emb_out) {
    int k = blockIdx.x;
    int t = threadIdx.x;  // 128, one float4 each
    int s = rowstart[k], e = rowstart[k + 1];
    float4 acc = {0.f, 0.f, 0.f, 0.f};
    for (int i = s; i < e; ++i) {
        int tok = tokenlist[i];
        float4 v = ((const float4*)(x + (size_t)tok * DIM))[t];
        acc.x += v.x; acc.y += v.y; acc.z += v.z; acc.w += v.w;
    }
    float4 w = ((const float4*)(ema_w + (size_t)k * DIM))[t];
    float cs = new_cs[k];
    float4 nw = {DECAY_F * w.x + OMD_F * acc.x, DECAY_F * w.y + OMD_F * acc.y,
                 DECAY_F * w.z + OMD_F * acc.z, DECAY_F * w.w + OMD_F * acc.w};
    ((float4*)(emaw_out + (size_t)k * DIM))[t] = nw;
    float4 eo = {nw.x / cs, nw.y / cs, nw.z / cs, nw.w / cs};
    ((float4*)(emb_out + (size_t)k * DIM))[t] = eo;
}

extern "C" void kernel_launch(void* const* d_in, const int* in_sizes, int n_in,
                              void* d_out, int out_size, void* d_ws, size_t ws_size,
                              hipStream_t stream) {
    const float* x      = (const float*)d_in[0];
    const float* emb    = (const float*)d_in[1];
    const float* ema_cs = (const float*)d_in[2];
    const float* ema_w  = (const float*)d_in[3];
    float* out = (float*)d_out;
    char*  ws  = (char*)d_ws;

    int*    counts   = (int*)ws;
    int*    cursors  = (int*)(ws + 32768);
    double* loss_sum = (double*)(ws + 65536);
    float*  enorm2   = (float*)(ws + 65600);
    int*    idx      = (int*)(ws + 98368);
    int*    tokenlist= (int*)(ws + 229440);
    int*    rowstart = (int*)(ws + 360512);

    // scratch in d_out regions that are dead until later kernels:
    f16* xh = (f16*)out;                       // [0, N*D) floats
    f16* xl = xh + (size_t)N_TOK * DIM;
    f16* eh = (f16*)(out + OFF_EMB);           // new_embedding slot
    f16* el = eh + (size_t)K_CODE * DIM;
    unsigned long long* bestu = (unsigned long long*)(out + OFF_EMAW);  // new_ema_w slot

    hipMemsetAsync(ws, 0, 65544, stream);   // counts + cursors + loss_sum

    split_k <<<(N_TOK * DIM) / 1024, 256, 0, stream>>>(x, xh, xl);
    split_k <<<(K_CODE * DIM) / 1024, 256, 0, stream>>>(emb, eh, el);
    enorm_k <<<K_CODE, 64, 0, stream>>>(emb, enorm2);
    argmin_mfma<<<dim3(N_TOK / 128, 4), 256, 0, stream>>>(xh, xl, eh, el, enorm2, bestu);
    bucket1_k<<<N_TOK / 256, 256, 0, stream>>>(bestu, idx, counts);
    prefix_k <<<1, 256, 0, stream>>>(counts, rowstart);
    scatter_k<<<N_TOK / 256, 256, 0, stream>>>(idx, rowstart, cursors, tokenlist);
    gather_q <<<2048, 256, 0, stream>>>(x, emb, idx, out, loss_sum);
    stats_k  <<<1, 256, 0, stream>>>(counts, ema_cs, loss_sum, out);
    dw_fin_k <<<K_CODE, 128, 0, stream>>>(x, ema_w, rowstart, tokenlist,
                                          out + OFF_CS, out + OFF_EMAW, out + OFF_EMB);
}

// Round 3
// 1023.519 us; speedup vs baseline: 1.0523x; 1.0523x over previous
//
#include <hip/hip_runtime.h>
#include <cstdint>
#include <math.h>

#define N_TOK 32768
#define K_CODE 8192
#define DIM 512

#define DECAY_F 0.99f
#define OMD_F   0.01f

// output layout (flat float32, concatenated in return order)
#define OFF_LOSS 16777216            // N*D
#define OFF_PERP 16777217
#define OFF_EMB  16777218            // new_embedding [K*D]
#define OFF_CS   20971522            // new_cs [K]
#define OFF_EMAW 20979714            // new_ema_w [K*D]

// workspace layout (bytes)
// [0, 32768)        counts_int [K] i32   (memset 0)
// [32768, 65536)    cursors [K] i32      (memset 0)
// [65536, 65544)    loss_sum double      (memset 0)
// [65600, 98368)    enorm2 [K] f32
// [98368, 229440)   idx [N] i32
// [229440, 360512)  tokenlist [N] i32
// [360512, 393284)  rowstart [K+1] i32
// bestu u64[N*4] lives in d_out's new_ema_w slot (dead until dw_fin_k)

typedef _Float16 f16;
typedef __attribute__((ext_vector_type(8))) _Float16 f16x8;
typedef __attribute__((ext_vector_type(4))) _Float16 f16x4;
typedef __attribute__((ext_vector_type(4))) float    f32x4;

// split fp32 -> (hi fp16, lo fp16); lo = RN16(x - (float)hi); x - hi exact in fp32
__global__ void split_k(const float* __restrict__ src, f16* __restrict__ hp,
                        f16* __restrict__ lp) {
    size_t gid = (size_t)blockIdx.x * 256 + threadIdx.x;
    float4 v = ((const float4*)src)[gid];
    f16 h0 = (f16)v.x, h1 = (f16)v.y, h2 = (f16)v.z, h3 = (f16)v.w;
    f16 l0 = (f16)(v.x - (float)h0), l1 = (f16)(v.y - (float)h1);
    f16 l2 = (f16)(v.z - (float)h2), l3 = (f16)(v.w - (float)h3);
    *(f16x4*)(hp + gid * 4) = (f16x4){h0, h1, h2, h3};
    *(f16x4*)(lp + gid * 4) = (f16x4){l0, l1, l2, l3};
}

__global__ void enorm_k(const float* __restrict__ emb, float* __restrict__ enorm2) {
    int k = blockIdx.x;
    int lane = threadIdx.x;  // 64
    const float4* row = (const float4*)(emb + (size_t)k * DIM);
    float4 a = row[lane];
    float4 b = row[lane + 64];
    float s = a.x*a.x + a.y*a.y + a.z*a.z + a.w*a.w
            + b.x*b.x + b.y*b.y + b.z*b.z + b.w*b.w;
    #pragma unroll
    for (int off = 32; off > 0; off >>= 1) s += __shfl_down(s, off);
    if (lane == 0) enorm2[k] = s;
}

// MFMA fused GEMM+argmin. 8-wave block: 256 tokens x 256-code tiles, sweeping K/4 codes.
// Double-buffered LDS (128 KB) + counted vmcnt: stage(s+1) -> vmcnt(8) -> s_barrier ->
// ds_read+MFMA -> s_barrier. Loads for step s+1 stay in flight across compute of step s.
// Wave grid 4x2: wave tile 64 rows x 128 cols (acc[4][8]).
// LDS tiles XOR-swizzled: physical colblock = logical ^ ((row>>1)&3)  (colblock = 16 B)
__global__ __launch_bounds__(512, 2) void argmin_mfma(
        const f16* __restrict__ xh, const f16* __restrict__ xl,
        const f16* __restrict__ eh, const f16* __restrict__ el,
        const float* __restrict__ enorm2,
        unsigned long long* __restrict__ bestu) {
    // [buf][region][256*32 halfs]; region 0=A hi, 1=A lo, 2=B hi, 3=B lo
    __shared__ f16 sL[2 * 4 * 8192];   // 128 KB

    const int tid  = threadIdx.x;
    const int lane = tid & 63;
    const int wave = tid >> 6;         // 0..7
    const int wr   = wave >> 1;        // 0..3 (row wave)
    const int wc   = wave & 1;         // 0..1 (col wave)
    const int m    = lane & 15;
    const int g4   = lane >> 4;
    const int cbp  = g4 ^ ((m >> 1) & 3);      // swizzled colblock for frag reads

    const int rowBase = blockIdx.x * 256;
    const int kBase   = blockIdx.y * (K_CODE / 4);

    // staging roles: region = wave>>1 (Ahi/Alo/Bhi/Blo), half = wave&1 (rows 0-127 / 128-255)
    // each wave stages 8 chunks of 16 rows x 32 halfs (1 KB) per step
    const int region = wave >> 1;
    const int half   = wave & 1;
    const int srow   = lane >> 2;
    const int scolh  = (((lane & 3) ^ ((lane >> 3) & 3)) << 3);  // swizzled source col (halfs)

    const f16* gbase = (region == 0) ? xh : (region == 1) ? xl : (region == 2) ? eh : el;

    auto stage = [&](int s) {
        int buf = s & 1;
        int d0  = (s & 15) * 32;
        int ktv = (s >> 4) * 256;
        size_t row0 = (region < 2) ? (size_t)(rowBase + half * 128)
                                   : (size_t)(kBase + ktv + half * 128);
        const f16* g = gbase + row0 * DIM + d0 + (size_t)srow * DIM + scolh;
        f16* dst = sL + buf * 32768 + region * 8192 + half * 4096 + (size_t)lane * 8;
        #pragma unroll
        for (int c = 0; c < 8; ++c) {
            __builtin_amdgcn_global_load_lds(
                (const __attribute__((address_space(1))) unsigned int*)(g + (size_t)c * 16 * DIM),
                (__attribute__((address_space(3))) unsigned int*)(dst + c * 512),
                16, 0, 0);
        }
    };

    float best[16];
    int   bidx[16];
    #pragma unroll
    for (int i = 0; i < 16; ++i) { best[i] = 3.4e38f; bidx[i] = 0; }

    stage(0);

    for (int kt8 = 0; kt8 < 8; ++kt8) {
        f32x4 acc[4][8];
        #pragma unroll
        for (int a = 0; a < 4; ++a)
            #pragma unroll
            for (int b = 0; b < 8; ++b)
                acc[a][b] = (f32x4){0.f, 0.f, 0.f, 0.f};

        for (int d16 = 0; d16 < 16; ++d16) {
            int s = kt8 * 16 + d16;
            if (s + 1 < 128) {
                stage(s + 1);
                asm volatile("s_waitcnt vmcnt(8)" ::: "memory");
            } else {
                asm volatile("s_waitcnt vmcnt(0)" ::: "memory");
            }
            __builtin_amdgcn_s_barrier();

            const f16* bA = sL + (s & 1) * 32768;
            f16x8 ah[4], al[4];
            #pragma unroll
            for (int rt = 0; rt < 4; ++rt) {
                int off = (wr * 64 + rt * 16 + m) * 32 + cbp * 8;
                ah[rt] = *(const f16x8*)(bA + off);
                al[rt] = *(const f16x8*)(bA + 8192 + off);
            }
            #pragma unroll
            for (int ct = 0; ct < 8; ++ct) {
                int off = (wc * 128 + ct * 16 + m) * 32 + cbp * 8;
                f16x8 bh = *(const f16x8*)(bA + 16384 + off);
                f16x8 bl = *(const f16x8*)(bA + 24576 + off);
                #pragma unroll
                for (int rt = 0; rt < 4; ++rt) {
                    acc[rt][ct] = __builtin_amdgcn_mfma_f32_16x16x32_f16(ah[rt], bl, acc[rt][ct], 0, 0, 0);
                    acc[rt][ct] = __builtin_amdgcn_mfma_f32_16x16x32_f16(al[rt], bh, acc[rt][ct], 0, 0, 0);
                    acc[rt][ct] = __builtin_amdgcn_mfma_f32_16x16x32_f16(ah[rt], bh, acc[rt][ct], 0, 0, 0);
                }
            }
            __builtin_amdgcn_s_barrier();
        }

        // dist = |e|^2 - 2 x.e ; running argmin (ascending col order, strict <)
        // register-only + enorm2 global reads; no LDS use -> outside the barrier schedule
        int colBase = kBase + kt8 * 256 + wc * 128;
        float e2[8];
        #pragma unroll
        for (int ct = 0; ct < 8; ++ct) e2[ct] = enorm2[colBase + ct * 16 + m];
        #pragma unroll
        for (int rt = 0; rt < 4; ++rt)
            #pragma unroll
            for (int reg = 0; reg < 4; ++reg) {
                float d = 3.4e38f; int c = 0;
                #pragma unroll
                for (int ct = 0; ct < 8; ++ct) {
                    float dist = e2[ct] - 2.0f * acc[rt][ct][reg];
                    if (dist < d) { d = dist; c = colBase + ct * 16 + m; }
                }
                int bi = rt * 4 + reg;
                if (d < best[bi]) { best[bi] = d; bidx[bi] = c; }
            }
    }

    __syncthreads();   // all waves done with sL tiles; reuse as combine scratch
    float* cd = (float*)sL;                 // [256]
    int*   ci = (int*)((char*)sL + 1024);   // [256]

    #pragma unroll
    for (int rt = 0; rt < 4; ++rt)
        #pragma unroll
        for (int reg = 0; reg < 4; ++reg) {
            float d = best[rt * 4 + reg];
            int  ix = bidx[rt * 4 + reg];
            #pragma unroll
            for (int off = 1; off < 16; off <<= 1) {
                float od = __shfl_xor(d, off);
                int   oi = __shfl_xor(ix, off);
                if (od < d || (od == d && oi < ix)) { d = od; ix = oi; }
            }
            best[rt * 4 + reg] = d;
            bidx[rt * 4 + reg] = ix;
            if (wc == 1 && m == 0) {
                int tl = rt * 16 + g4 * 4 + reg;
                cd[wr * 64 + tl] = d;
                ci[wr * 64 + tl] = ix;
            }
        }
    __syncthreads();
    if (wc == 0 && m == 0) {
        #pragma unroll
        for (int rt = 0; rt < 4; ++rt)
            #pragma unroll
            for (int reg = 0; reg < 4; ++reg) {
                int tl = rt * 16 + g4 * 4 + reg;
                float d = best[rt * 4 + reg];
                int  ix = bidx[rt * 4 + reg];
                float od = cd[wr * 64 + tl];
                int   oi = ci[wr * 64 + tl];
                if (od < d || (od == d && oi < ix)) { d = od; ix = oi; }
                unsigned int fs = __float_as_uint(d);
                unsigned int key = fs ^ ((fs & 0x80000000u) ? 0xFFFFFFFFu : 0x80000000u);
                unsigned long long u = ((unsigned long long)key << 32) | (unsigned int)ix;
                bestu[(size_t)(rowBase + wr * 64 + tl) * 4 + blockIdx.y] = u;
            }
    }
}

// per token: min over 4 slots -> idx, count histogram
__global__ void bucket1_k(const unsigned long long* __restrict__ bestu,
                          int* __restrict__ idx, int* __restrict__ counts) {
    int n = blockIdx.x * 256 + threadIdx.x;
    const unsigned long long* p = bestu + (size_t)n * 4;
    unsigned long long u = p[0];
    if (p[1] < u) u = p[1];
    if (p[2] < u) u = p[2];
    if (p[3] < u) u = p[3];
    int code = (int)(u & 0xFFFFFFFFull);
    idx[n] = code;
    atomicAdd(&counts[code], 1);
}

// exclusive prefix sum over counts (single block)
__global__ void prefix_k(const int* __restrict__ counts, int* __restrict__ rowstart) {
    __shared__ int part[256];
    __shared__ int partsc[257];
    int t = threadIdx.x;
    int base = t * 32;
    int c[32];
    int s = 0;
    #pragma unroll
    for (int j = 0; j < 32; ++j) { c[j] = counts[base + j]; s += c[j]; }
    part[t] = s;
    __syncthreads();
    if (t == 0) {
        int r = 0;
        for (int i = 0; i < 256; ++i) { partsc[i] = r; r += part[i]; }
        partsc[256] = r;
    }
    __syncthreads();
    int off = partsc[t];
    #pragma unroll
    for (int j = 0; j < 32; ++j) { rowstart[base + j] = off; off += c[j]; }
    if (t == 255) rowstart[K_CODE] = partsc[256];
}

// scatter tokens into CSR lists
__global__ void scatter_k(const int* __restrict__ idx, const int* __restrict__ rowstart,
                          int* __restrict__ cursors, int* __restrict__ tokenlist) {
    int n = blockIdx.x * 256 + threadIdx.x;
    int code = idx[n];
    int pos = atomicAdd(&cursors[code], 1);
    tokenlist[rowstart[code] + pos] = n;
}

// gather q = emb[idx] and exact commitment-loss sum
__global__ void gather_q(const float* __restrict__ x, const float* __restrict__ emb,
                         const int* __restrict__ idx, float* __restrict__ q,
                         double* __restrict__ loss_sum) {
    float ls = 0.f;
    #pragma unroll
    for (int it = 0; it < 8; ++it) {
        size_t g = (size_t)blockIdx.x * 256 + threadIdx.x + (size_t)it * 524288;
        int n = (int)(g >> 7);
        int c = (int)(g & 127);
        float4 ev = ((const float4*)emb)[(size_t)idx[n] * 128 + c];
        float4 xv = ((const float4*)x)[g];
        ((float4*)q)[g] = ev;
        float dx = ev.x - xv.x, dy = ev.y - xv.y, dz = ev.z - xv.z, dw = ev.w - xv.w;
        ls += dx*dx + dy*dy + dz*dz + dw*dw;
    }
    #pragma unroll
    for (int off = 32; off > 0; off >>= 1) ls += __shfl_down(ls, off);
    __shared__ float wsum[4];
    int t = threadIdx.x;
    if ((t & 63) == 0) wsum[t >> 6] = ls;
    __syncthreads();
    if (t == 0) atomicAdd(loss_sum, (double)(wsum[0] + wsum[1] + wsum[2] + wsum[3]));
}

// single block: new_cs normalization, perplexity, loss scalar
__global__ void stats_k(const int* __restrict__ counts, const float* __restrict__ ema_cs,
                        const double* __restrict__ loss_sum, float* __restrict__ out) {
    __shared__ float sraw[K_CODE];
    __shared__ double rn[4], rp[4];
    __shared__ float s_scale;
    int t = threadIdx.x;  // 256
    double ntot = 0.0, pent = 0.0;
    for (int k = t; k < K_CODE; k += 256) {
        float c = (float)counts[k];
        float raw = DECAY_F * ema_cs[k] + OMD_F * c;
        sraw[k] = raw;
        ntot += (double)raw;
        float p = c * (1.0f / N_TOK);
        pent += (double)(p * logf(p + 1e-10f));
    }
    #pragma unroll
    for (int off = 32; off > 0; off >>= 1) {
        ntot += __shfl_down(ntot, off);
        pent += __shfl_down(pent, off);
    }
    if ((t & 63) == 0) { rn[t >> 6] = ntot; rp[t >> 6] = pent; }
    __syncthreads();
    if (t == 0) {
        double nt = rn[0] + rn[1] + rn[2] + rn[3];
        double pe = rp[0] + rp[1] + rp[2] + rp[3];
        s_scale = (float)(nt / (nt + (double)K_CODE * 1e-5));
        out[OFF_LOSS] = (float)(0.25 * (*loss_sum) / ((double)N_TOK * (double)DIM));
        out[OFF_PERP] = (float)exp(-pe);
    }
    __syncthreads();
    float scale = s_scale;
    for (int k = t; k < K_CODE; k += 256)
        out[OFF_CS + k] = (sraw[k] + 1e-5f) * scale;
}

// per code: dw = sum of assigned x rows; fused EMA + divide epilogue
__global__ __launch_bounds__(128) void dw_fin_k(
        const float* __restrict__ x, const float* __restrict__ ema_w,
        const int* __restrict__ rowstart, const int* __restrict__ tokenlist,
        const float* __restrict__ new_cs,
        float* __restrict__ emaw_out, float* __restrict__ emb_out) {
    int k = blockIdx.x;
    int t = threadIdx.x;  // 128, one float4 each
    int s = rowstart[k], e = rowstart[k + 1];
    float4 acc = {0.f, 0.f, 0.f, 0.f};
    for (int i = s; i < e; ++i) {
        int tok = tokenlist[i];
        float4 v = ((const float4*)(x + (size_t)tok * DIM))[t];
        acc.x += v.x; acc.y += v.y; acc.z += v.z; acc.w += v.w;
    }
    float4 w = ((const float4*)(ema_w + (size_t)k * DIM))[t];
    float cs = new_cs[k];
    float4 nw = {DECAY_F * w.x + OMD_F * acc.x, DECAY_F * w.y + OMD_F * acc.y,
                 DECAY_F * w.z + OMD_F * acc.z, DECAY_F * w.w + OMD_F * acc.w};
    ((float4*)(emaw_out + (size_t)k * DIM))[t] = nw;
    float4 eo = {nw.x / cs, nw.y / cs, nw.z / cs, nw.w / cs};
    ((float4*)(emb_out + (size_t)k * DIM))[t] = eo;
}

extern "C" void kernel_launch(void* const* d_in, const int* in_sizes, int n_in,
                              void* d_out, int out_size, void* d_ws, size_t ws_size,
                              hipStream_t stream) {
    const float* x      = (const float*)d_in[0];
    const float* emb    = (const float*)d_in[1];
    const float* ema_cs = (const float*)d_in[2];
    const float* ema_w  = (const float*)d_in[3];
    float* out = (float*)d_out;
    char*  ws  = (char*)d_ws;

    int*    counts   = (int*)ws;
    int*    cursors  = (int*)(ws + 32768);
    double* loss_sum = (double*)(ws + 65536);
    float*  enorm2   = (float*)(ws + 65600);
    int*    idx      = (int*)(ws + 98368);
    int*    tokenlist= (int*)(ws + 229440);
    int*    rowstart = (int*)(ws + 360512);

    // scratch in d_out regions that are dead until later kernels:
    f16* xh = (f16*)out;                       // [0, N*D) floats
    f16* xl = xh + (size_t)N_TOK * DIM;
    f16* eh = (f16*)(out + OFF_EMB);           // new_embedding slot
    f16* el = eh + (size_t)K_CODE * DIM;
    unsigned long long* bestu = (unsigned long long*)(out + OFF_EMAW);  // new_ema_w slot

    hipMemsetAsync(ws, 0, 65544, stream);   // counts + cursors + loss_sum

    split_k <<<(N_TOK * DIM) / 1024, 256, 0, stream>>>(x, xh, xl);
    split_k <<<(K_CODE * DIM) / 1024, 256, 0, stream>>>(emb, eh, el);
    enorm_k <<<K_CODE, 64, 0, stream>>>(emb, enorm2);
    argmin_mfma<<<dim3(N_TOK / 256, 4), 512, 0, stream>>>(xh, xl, eh, el, enorm2, bestu);
    bucket1_k<<<N_TOK / 256, 256, 0, stream>>>(bestu, idx, counts);
    prefix_k <<<1, 256, 0, stream>>>(counts, rowstart);
    scatter_k<<<N_TOK / 256, 256, 0, stream>>>(idx, rowstart, cursors, tokenlist);
    gather_q <<<2048, 256, 0, stream>>>(x, emb, idx, out, loss_sum);
    stats_k  <<<1, 256, 0, stream>>>(counts, ema_cs, loss_sum, out);
    dw_fin_k <<<K_CODE, 128, 0, stream>>>(x, ema_w, rowstart, tokenlist,
                                          out + OFF_CS, out + OFF_EMAW, out + OFF_EMB);
}